// Round 1
// baseline (1272.628 us; speedup 1.0000x reference)
//
#include <hip/hip_runtime.h>

#define B_SZ  4096
#define NB    64
#define DIM   512
#define INTER 128
#define EPSV  1e-5f
#define NLOG2E 1.4426950408889634f

using f32x4  = __attribute__((ext_vector_type(4))) float;
using bf16x8 = __attribute__((ext_vector_type(8))) __bf16;
using short8 = __attribute__((ext_vector_type(8))) short;

static __device__ __forceinline__ unsigned short f2bf(float f) {
    union { float f; unsigned u; } v; v.f = f;
    return (unsigned short)((v.u + 0x7fffu + ((v.u >> 16) & 1u)) >> 16);
}

static __device__ __forceinline__ f32x4 mfma16(short8 a, short8 b, f32x4 c) {
    return __builtin_amdgcn_mfma_f32_16x16x32_bf16(
        __builtin_bit_cast(bf16x8, a), __builtin_bit_cast(bf16x8, b), c, 0, 0, 0);
}

// ---- prep: W1,W2 -> bf16 ; fold BN constants into scale/bias -------------
// sc2/bi2 are pre-multiplied by -log2(e) so gemm2's sigmoid is
// w = rcp(1 + exp2(y*sc2' + bi2')).
__global__ void prep_kernel(
    const float4* __restrict__ W1, const float4* __restrict__ W2,
    const float* __restrict__ b1, const float* __restrict__ g1,
    const float* __restrict__ beta1, const float* __restrict__ m1,
    const float* __restrict__ v1,
    const float* __restrict__ b2, const float* __restrict__ g2,
    const float* __restrict__ beta2, const float* __restrict__ m2,
    const float* __restrict__ v2,
    ushort4* __restrict__ w1bf, ushort4* __restrict__ w2bf,
    float* __restrict__ sc1, float* __restrict__ bi1,
    float* __restrict__ sc2, float* __restrict__ bi2)
{
    int idx = blockIdx.x * blockDim.x + threadIdx.x;  // 0 .. 1048575
    float4 a = W1[idx];
    ushort4 pa; pa.x = f2bf(a.x); pa.y = f2bf(a.y); pa.z = f2bf(a.z); pa.w = f2bf(a.w);
    w1bf[idx] = pa;
    float4 b = W2[idx];
    ushort4 pb; pb.x = f2bf(b.x); pb.y = f2bf(b.y); pb.z = f2bf(b.z); pb.w = f2bf(b.w);
    w2bf[idx] = pb;
    if (idx < NB * INTER) {
        float s = g1[idx] * rsqrtf(v1[idx] + EPSV);
        sc1[idx] = s;
        bi1[idx] = (b1[idx] - m1[idx]) * s + beta1[idx];
    }
    if (idx < NB * DIM) {
        float s = g2[idx] * rsqrtf(v2[idx] + EPSV);
        sc2[idx] = -NLOG2E * s;
        bi2[idx] = -NLOG2E * ((b2[idx] - m2[idx]) * s + beta2[idx]);
    }
}

// ---- sum over branches: s[b,d] = sum_n t[b,n,d], stored bf16 -------------
__global__ void sum_kernel(const float* __restrict__ t, unsigned short* __restrict__ sbf)
{
    int tid = threadIdx.x;
    int b = blockIdx.x * 2 + (tid >> 7);
    int c = tid & 127;                       // float4 column index (0..127)
    const float4* tb = (const float4*)t + (size_t)b * (NB * DIM / 4) + c;
    float4 acc = tb[0];
    for (int n = 1; n < NB; ++n) {
        float4 v = tb[n * (DIM / 4)];
        acc.x += v.x; acc.y += v.y; acc.z += v.z; acc.w += v.w;
    }
    ushort4 o; o.x = f2bf(acc.x); o.y = f2bf(acc.y); o.z = f2bf(acc.z); o.w = f2bf(acc.w);
    ((ushort4*)sbf)[(size_t)b * 128 + c] = o;
}

__global__ void zero_kernel(float4* __restrict__ out)
{
    out[blockIdx.x * 256 + threadIdx.x] = (float4){0.f, 0.f, 0.f, 0.f};
}

// ---- phase A: h[n][b][i] = relu(BN1(s @ W1[n]^T)), bf16, n-major ---------
// grid (32 btiles, 64 n), 256 threads = 4 waves.
// OPERAND-SWAPPED: A = W1 rows (i), B = s rows (b), so C rows = i, C cols = b.
// Each lane then owns 4 CONSECUTIVE i -> packed ushort4 stores (16x 8B
// instead of 64x scalar 2B) and float4 sc1/bi1 loads.
__global__ __launch_bounds__(256) void gemm1_kernel(
    const unsigned short* __restrict__ sbf,
    const unsigned short* __restrict__ w1bf,
    const float* __restrict__ sc1, const float* __restrict__ bi1,
    unsigned short* __restrict__ h)
{
    const int btile = blockIdx.x;       // 0..31
    const int n     = blockIdx.y;       // 0..63
    const int tid  = threadIdx.x;
    const int w    = tid >> 6;
    const int lane = tid & 63;
    const int quad = lane >> 4;
    const int l16  = lane & 15;
    const int i0 = (w & 1) * 64;                    // i-half of this wave
    const int b0 = btile * 128 + (w >> 1) * 64;     // b-half of this wave

    f32x4 acc[4][4];
    #pragma unroll
    for (int a = 0; a < 4; ++a)
        #pragma unroll
        for (int c = 0; c < 4; ++c) acc[a][c] = (f32x4){0.f, 0.f, 0.f, 0.f};

    const unsigned short* w1n = w1bf + (size_t)n * (INTER * DIM);
    const unsigned short* abase = w1n + (size_t)(i0 + l16) * DIM + (quad << 3); // A = W1
    const unsigned short* bbase = sbf + (size_t)(b0 + l16) * DIM + (quad << 3); // B = s

    #pragma unroll 2
    for (int s = 0; s < 16; ++s) {
        short8 af[4], bf[4];
        #pragma unroll
        for (int a = 0; a < 4; ++a)
            af[a] = *(const short8*)(abase + (size_t)(a * 16) * DIM + s * 32);
        #pragma unroll
        for (int c = 0; c < 4; ++c)
            bf[c] = *(const short8*)(bbase + (size_t)(c * 16) * DIM + s * 32);
        #pragma unroll
        for (int a = 0; a < 4; ++a)
            #pragma unroll
            for (int c = 0; c < 4; ++c)
                acc[a][c] = mfma16(af[a], bf[c], acc[a][c]);
    }

    // epilogue: BN1 + ReLU -> h[n][b][i] (bf16), vectorized over i
    unsigned short* hn = h + (size_t)n * (B_SZ * INTER);
    #pragma unroll
    for (int a = 0; a < 4; ++a) {
        const int i = i0 + a * 16 + (quad << 2);            // multiple of 4
        const f32x4 sv = *(const f32x4*)(sc1 + n * INTER + i);
        const f32x4 bv = *(const f32x4*)(bi1 + n * INTER + i);
        #pragma unroll
        for (int c = 0; c < 4; ++c) {
            const int b = b0 + c * 16 + l16;
            ushort4 o;
            float v0 = acc[a][c][0] * sv[0] + bv[0]; v0 = v0 > 0.f ? v0 : 0.f;
            float v1 = acc[a][c][1] * sv[1] + bv[1]; v1 = v1 > 0.f ? v1 : 0.f;
            float v2 = acc[a][c][2] * sv[2] + bv[2]; v2 = v2 > 0.f ? v2 : 0.f;
            float v3 = acc[a][c][3] * sv[3] + bv[3]; v3 = v3 > 0.f ? v3 : 0.f;
            o.x = f2bf(v0); o.y = f2bf(v1); o.z = f2bf(v2); o.w = f2bf(v3);
            *(ushort4*)(hn + (size_t)b * INTER + i) = o;
        }
    }
}

// ---- phase B: out[b,d] += sum_n sigmoid(BN2(h_n @ W2[n]^T)) * t * 3 ------
// grid (64 btiles, 8 dtiles, 4 ngroups), 256 threads = 4 waves.
// OPERAND-SWAPPED: A = W2 rows (d), B = h rows (b) -> C rows = d.
// Each lane owns 4 consecutive d, so t / sc2 / bi2 are float4 loads.
// t for branch n+1 is prefetched (double-buffered) while branch n computes,
// hiding the ~900-cycle HBM miss.
__global__ __launch_bounds__(256) void gemm2_kernel(
    const float* __restrict__ t,
    const unsigned short* __restrict__ h,
    const unsigned short* __restrict__ w2bf,
    const float* __restrict__ sc2, const float* __restrict__ bi2,
    float* __restrict__ out)
{
    const int btile = blockIdx.x;   // 0..63
    const int dtile = blockIdx.y;   // 0..7
    const int ng    = blockIdx.z;   // 0..3 (16 branches each)
    const int tid  = threadIdx.x;
    const int w    = tid >> 6;
    const int lane = tid & 63;
    const int quad = lane >> 4;
    const int l16  = lane & 15;
    const int d0 = dtile * 64;
    const int b  = btile * 64 + w * 16 + l16;   // this lane's b row (C col)
    const int dq = d0 + (quad << 2);            // d base of this lane's acc rows

    f32x4 oacc[4];
    #pragma unroll
    for (int c = 0; c < 4; ++c) oacc[c] = (f32x4){0.f, 0.f, 0.f, 0.f};

    const unsigned short* hb  = h + (size_t)(ng * 16) * (B_SZ * INTER)
                              + (size_t)b * INTER + (quad << 3);
    const unsigned short* w2b = w2bf + (size_t)(ng * 16) * (DIM * INTER)
                              + (size_t)(d0 + l16) * INTER + (quad << 3);
    const float* tb = t + ((size_t)b * NB + ng * 16) * DIM + dq;

    // preload t for first branch of this group
    f32x4 tc[4], tn[4];
    #pragma unroll
    for (int c = 0; c < 4; ++c) tc[c] = *(const f32x4*)(tb + c * 16);

    for (int k = 0; k < 16; ++k) {
        // prefetch t for branch k+1 (consumed next iteration)
        if (k < 15) {
            const float* tnx = tb + (size_t)(k + 1) * DIM;
            #pragma unroll
            for (int c = 0; c < 4; ++c) tn[c] = *(const f32x4*)(tnx + c * 16);
        }

        const unsigned short* hn  = hb  + (size_t)k * (B_SZ * INTER);
        const unsigned short* w2n = w2b + (size_t)k * (DIM * INTER);
        f32x4 yacc[4];
        #pragma unroll
        for (int c = 0; c < 4; ++c) yacc[c] = (f32x4){0.f, 0.f, 0.f, 0.f};

        #pragma unroll
        for (int s = 0; s < 4; ++s) {
            short8 bfh = *(const short8*)(hn + s * 32);
            #pragma unroll
            for (int c = 0; c < 4; ++c) {
                short8 af = *(const short8*)(w2n + (size_t)(c * 16) * INTER + s * 32);
                yacc[c] = mfma16(af, bfh, yacc[c]);
            }
        }

        // BN2 + sigmoid + gate with t   (sc2/bi2 pre-scaled by -log2e)
        const int n = ng * 16 + k;
        const float* scn = sc2 + (size_t)n * DIM + dq;
        const float* bin = bi2 + (size_t)n * DIM + dq;
        #pragma unroll
        for (int c = 0; c < 4; ++c) {
            const f32x4 sv = *(const f32x4*)(scn + c * 16);
            const f32x4 bv = *(const f32x4*)(bin + c * 16);
            #pragma unroll
            for (int r = 0; r < 4; ++r) {
                float e  = yacc[c][r] * sv[r] + bv[r];          // = -y*log2e
                float wv = __builtin_amdgcn_rcpf(1.f + __builtin_amdgcn_exp2f(e));
                oacc[c][r] += wv * tc[c][r];
            }
        }
        #pragma unroll
        for (int c = 0; c < 4; ++c) tc[c] = tn[c];
    }

    #pragma unroll
    for (int c = 0; c < 4; ++c) {
        #pragma unroll
        for (int r = 0; r < 4; ++r) {
            unsafeAtomicAdd(&out[(size_t)b * DIM + dq + c * 16 + r], oacc[c][r] * 3.0f);
        }
    }
}

extern "C" void kernel_launch(void* const* d_in, const int* in_sizes, int n_in,
                              void* d_out, int out_size, void* d_ws, size_t ws_size,
                              hipStream_t stream)
{
    const float* t     = (const float*)d_in[0];
    const float* W1    = (const float*)d_in[1];
    const float* b1    = (const float*)d_in[2];
    const float* g1    = (const float*)d_in[3];
    const float* beta1 = (const float*)d_in[4];
    const float* m1    = (const float*)d_in[5];
    const float* v1    = (const float*)d_in[6];
    const float* W2    = (const float*)d_in[7];
    const float* b2    = (const float*)d_in[8];
    const float* g2    = (const float*)d_in[9];
    const float* beta2 = (const float*)d_in[10];
    const float* m2    = (const float*)d_in[11];
    const float* v2    = (const float*)d_in[12];

    char* ws = (char*)d_ws;
    unsigned short* w1bf = (unsigned short*)(ws);                 //  8,388,608 B
    unsigned short* w2bf = (unsigned short*)(ws + 8388608);       //  8,388,608 B
    unsigned short* sbf  = (unsigned short*)(ws + 16777216);      //  4,194,304 B
    float* sc1 = (float*)(ws + 20971520);                         //     32,768 B
    float* bi1 = (float*)(ws + 21004288);                         //     32,768 B
    float* sc2 = (float*)(ws + 21037056);                         //    131,072 B
    float* bi2 = (float*)(ws + 21168128);                         //    131,072 B
    unsigned short* hbuf = (unsigned short*)(ws + 21299200);      // 67,108,864 B

    prep_kernel<<<4096, 256, 0, stream>>>(
        (const float4*)W1, (const float4*)W2,
        b1, g1, beta1, m1, v1, b2, g2, beta2, m2, v2,
        (ushort4*)w1bf, (ushort4*)w2bf, sc1, bi1, sc2, bi2);

    sum_kernel<<<2048, 256, 0, stream>>>(t, sbf);

    zero_kernel<<<2048, 256, 0, stream>>>((float4*)d_out);

    gemm1_kernel<<<dim3(32, 64), 256, 0, stream>>>(sbf, w1bf, sc1, bi1, hbuf);

    gemm2_kernel<<<dim3(64, 8, 4), 256, 0, stream>>>(t, hbuf, w2bf, sc2, bi2, (float*)d_out);
}

// Round 2
// 1186.345 us; speedup vs baseline: 1.0727x; 1.0727x over previous
//
#include <hip/hip_runtime.h>

#define B_SZ  4096
#define NB    64
#define DIM   512
#define INTER 128
#define EPSV  1e-5f
#define NLOG2E 1.4426950408889634f

using f32x4  = __attribute__((ext_vector_type(4))) float;
using bf16x8 = __attribute__((ext_vector_type(8))) __bf16;
using short8 = __attribute__((ext_vector_type(8))) short;

static __device__ __forceinline__ unsigned short f2bf(float f) {
    union { float f; unsigned u; } v; v.f = f;
    return (unsigned short)((v.u + 0x7fffu + ((v.u >> 16) & 1u)) >> 16);
}

static __device__ __forceinline__ f32x4 mfma16(short8 a, short8 b, f32x4 c) {
    return __builtin_amdgcn_mfma_f32_16x16x32_bf16(
        __builtin_bit_cast(bf16x8, a), __builtin_bit_cast(bf16x8, b), c, 0, 0, 0);
}

// ---- prep: W1,W2 -> bf16 ; fold BN constants into scale/bias -------------
// sc2/bi2 are pre-multiplied by -log2(e) so gemm2's sigmoid is
// w = rcp(1 + exp2(y*sc2' + bi2')).
__global__ void prep_kernel(
    const float4* __restrict__ W1, const float4* __restrict__ W2,
    const float* __restrict__ b1, const float* __restrict__ g1,
    const float* __restrict__ beta1, const float* __restrict__ m1,
    const float* __restrict__ v1,
    const float* __restrict__ b2, const float* __restrict__ g2,
    const float* __restrict__ beta2, const float* __restrict__ m2,
    const float* __restrict__ v2,
    ushort4* __restrict__ w1bf, ushort4* __restrict__ w2bf,
    float* __restrict__ sc1, float* __restrict__ bi1,
    float* __restrict__ sc2, float* __restrict__ bi2)
{
    int idx = blockIdx.x * blockDim.x + threadIdx.x;  // 0 .. 1048575
    float4 a = W1[idx];
    ushort4 pa; pa.x = f2bf(a.x); pa.y = f2bf(a.y); pa.z = f2bf(a.z); pa.w = f2bf(a.w);
    w1bf[idx] = pa;
    float4 b = W2[idx];
    ushort4 pb; pb.x = f2bf(b.x); pb.y = f2bf(b.y); pb.z = f2bf(b.z); pb.w = f2bf(b.w);
    w2bf[idx] = pb;
    if (idx < NB * INTER) {
        float s = g1[idx] * rsqrtf(v1[idx] + EPSV);
        sc1[idx] = s;
        bi1[idx] = (b1[idx] - m1[idx]) * s + beta1[idx];
    }
    if (idx < NB * DIM) {
        float s = g2[idx] * rsqrtf(v2[idx] + EPSV);
        sc2[idx] = -NLOG2E * s;
        bi2[idx] = -NLOG2E * ((b2[idx] - m2[idx]) * s + beta2[idx]);
    }
}

// ---- sum over branches: s[b,d] = sum_n t[b,n,d], stored bf16 -------------
__global__ void sum_kernel(const float* __restrict__ t, unsigned short* __restrict__ sbf)
{
    int tid = threadIdx.x;
    int b = blockIdx.x * 2 + (tid >> 7);
    int c = tid & 127;                       // float4 column index (0..127)
    const float4* tb = (const float4*)t + (size_t)b * (NB * DIM / 4) + c;
    float4 acc = tb[0];
    for (int n = 1; n < NB; ++n) {
        float4 v = tb[n * (DIM / 4)];
        acc.x += v.x; acc.y += v.y; acc.z += v.z; acc.w += v.w;
    }
    ushort4 o; o.x = f2bf(acc.x); o.y = f2bf(acc.y); o.z = f2bf(acc.z); o.w = f2bf(acc.w);
    ((ushort4*)sbf)[(size_t)b * 128 + c] = o;
}

__global__ void zero_kernel(float4* __restrict__ out)
{
    out[blockIdx.x * 256 + threadIdx.x] = (float4){0.f, 0.f, 0.f, 0.f};
}

// ---- phase A: h[n][b][i] = relu(BN1(s @ W1[n]^T)), bf16, n-major ---------
// grid (32 btiles, 64 n), 256 threads = 4 waves.
// OPERAND-SWAPPED: A = W1 rows (i), B = s rows (b), so C rows = i, C cols = b.
// Each lane then owns 4 CONSECUTIVE i -> packed ushort4 stores and float4
// sc1/bi1 loads.
__global__ __launch_bounds__(256) void gemm1_kernel(
    const unsigned short* __restrict__ sbf,
    const unsigned short* __restrict__ w1bf,
    const float* __restrict__ sc1, const float* __restrict__ bi1,
    unsigned short* __restrict__ h)
{
    const int btile = blockIdx.x;       // 0..31
    const int n     = blockIdx.y;       // 0..63
    const int tid  = threadIdx.x;
    const int w    = tid >> 6;
    const int lane = tid & 63;
    const int quad = lane >> 4;
    const int l16  = lane & 15;
    const int i0 = (w & 1) * 64;                    // i-half of this wave
    const int b0 = btile * 128 + (w >> 1) * 64;     // b-half of this wave

    f32x4 acc[4][4];
    #pragma unroll
    for (int a = 0; a < 4; ++a)
        #pragma unroll
        for (int c = 0; c < 4; ++c) acc[a][c] = (f32x4){0.f, 0.f, 0.f, 0.f};

    const unsigned short* w1n = w1bf + (size_t)n * (INTER * DIM);
    const unsigned short* abase = w1n + (size_t)(i0 + l16) * DIM + (quad << 3); // A = W1
    const unsigned short* bbase = sbf + (size_t)(b0 + l16) * DIM + (quad << 3); // B = s

    #pragma unroll 2
    for (int s = 0; s < 16; ++s) {
        short8 af[4], bf[4];
        #pragma unroll
        for (int a = 0; a < 4; ++a)
            af[a] = *(const short8*)(abase + (size_t)(a * 16) * DIM + s * 32);
        #pragma unroll
        for (int c = 0; c < 4; ++c)
            bf[c] = *(const short8*)(bbase + (size_t)(c * 16) * DIM + s * 32);
        #pragma unroll
        for (int a = 0; a < 4; ++a)
            #pragma unroll
            for (int c = 0; c < 4; ++c)
                acc[a][c] = mfma16(af[a], bf[c], acc[a][c]);
    }

    // epilogue: BN1 + ReLU -> h[n][b][i] (bf16), vectorized over i
    unsigned short* hn = h + (size_t)n * (B_SZ * INTER);
    #pragma unroll
    for (int a = 0; a < 4; ++a) {
        const int i = i0 + a * 16 + (quad << 2);            // multiple of 4
        const f32x4 sv = *(const f32x4*)(sc1 + n * INTER + i);
        const f32x4 bv = *(const f32x4*)(bi1 + n * INTER + i);
        #pragma unroll
        for (int c = 0; c < 4; ++c) {
            const int b = b0 + c * 16 + l16;
            ushort4 o;
            float v0 = acc[a][c][0] * sv[0] + bv[0]; v0 = v0 > 0.f ? v0 : 0.f;
            float v1 = acc[a][c][1] * sv[1] + bv[1]; v1 = v1 > 0.f ? v1 : 0.f;
            float v2 = acc[a][c][2] * sv[2] + bv[2]; v2 = v2 > 0.f ? v2 : 0.f;
            float v3 = acc[a][c][3] * sv[3] + bv[3]; v3 = v3 > 0.f ? v3 : 0.f;
            o.x = f2bf(v0); o.y = f2bf(v1); o.z = f2bf(v2); o.w = f2bf(v3);
            *(ushort4*)(hn + (size_t)b * INTER + i) = o;
        }
    }
}

// ---- phase B: out[b,d] += sum_n sigmoid(BN2(h_n @ W2[n]^T)) * t * 3 ------
// grid (64 btiles, 8 dtiles, 4 ngroups), 256 threads = 4 waves.
// ROUND-0 MAPPING (A = h rows -> C rows = b, C cols = d): 16 l16-lanes hit
// 16 consecutive d => t loads and out atomics are line-coalesced, VGPR ~44
// => 8 waves/SIMD. The 16 t scalar loads for branch n are ISSUED AT THE TOP
// of iteration n (no deps on MFMA) so the HBM miss overlaps fragment loads
// + 16 MFMAs; grid z=4 supplies 8 blocks/CU of latency-hiding waves.
__global__ __launch_bounds__(256) void gemm2_kernel(
    const float* __restrict__ t,
    const unsigned short* __restrict__ h,
    const unsigned short* __restrict__ w2bf,
    const float* __restrict__ sc2, const float* __restrict__ bi2,
    float* __restrict__ out)
{
    const int btile = blockIdx.x;   // 0..63
    const int dtile = blockIdx.y;   // 0..7
    const int ng    = blockIdx.z;   // 0..3 (16 branches each)
    const int tid  = threadIdx.x;
    const int w    = tid >> 6;
    const int lane = tid & 63;
    const int quad = lane >> 4;
    const int l16  = lane & 15;
    const int d0 = dtile * 64;

    f32x4 oacc[4];
    #pragma unroll
    for (int c = 0; c < 4; ++c) oacc[c] = (f32x4){0.f, 0.f, 0.f, 0.f};

    const unsigned short* habase =
        h + (size_t)(ng * 16) * (B_SZ * INTER)
          + (size_t)(btile * 64 + w * 16 + l16) * INTER + (quad << 3);
    const unsigned short* w2base =
        w2bf + (size_t)(ng * 16) * (DIM * INTER)
             + (size_t)(d0 + l16) * INTER + (quad << 3);
    // lane's t base: rows m = btile*64+w*16+quad*4+r, col d = d0+c*16+l16
    const float* tlane =
        t + ((size_t)(btile * 64 + w * 16 + quad * 4) * NB + ng * 16) * DIM
          + d0 + l16;

    for (int k = 0; k < 16; ++k) {
        // issue all 16 t loads for this branch FIRST (coalesced: 16 lanes
        // per 64B line); they are consumed only after the MFMA block.
        float tv[4][4];
        #pragma unroll
        for (int c = 0; c < 4; ++c)
            #pragma unroll
            for (int r = 0; r < 4; ++r)
                tv[c][r] = tlane[((size_t)r * NB + k) * DIM + c * 16];

        const unsigned short* hn  = habase + (size_t)k * (B_SZ * INTER);
        const unsigned short* w2n = w2base + (size_t)k * (DIM * INTER);
        f32x4 yacc[4];
        #pragma unroll
        for (int c = 0; c < 4; ++c) yacc[c] = (f32x4){0.f, 0.f, 0.f, 0.f};

        #pragma unroll
        for (int s = 0; s < 4; ++s) {
            short8 af = *(const short8*)(hn + s * 32);
            #pragma unroll
            for (int c = 0; c < 4; ++c) {
                short8 bf = *(const short8*)(w2n + (size_t)(c * 16) * INTER + s * 32);
                yacc[c] = mfma16(af, bf, yacc[c]);
            }
        }

        // BN2 + sigmoid + gate with t   (sc2/bi2 pre-scaled by -log2e)
        const int n = ng * 16 + k;
        #pragma unroll
        for (int c = 0; c < 4; ++c) {
            const int d = d0 + c * 16 + l16;
            const float sc = sc2[(size_t)n * DIM + d];
            const float bi = bi2[(size_t)n * DIM + d];
            #pragma unroll
            for (int r = 0; r < 4; ++r) {
                float e  = yacc[c][r] * sc + bi;            // = -y*log2e
                float wv = __builtin_amdgcn_rcpf(1.f + __builtin_amdgcn_exp2f(e));
                oacc[c][r] += wv * tv[c][r];
            }
        }
    }

    #pragma unroll
    for (int c = 0; c < 4; ++c) {
        const int d = d0 + c * 16 + l16;
        #pragma unroll
        for (int r = 0; r < 4; ++r) {
            const int m = btile * 64 + w * 16 + quad * 4 + r;
            unsafeAtomicAdd(&out[(size_t)m * DIM + d], oacc[c][r] * 3.0f);
        }
    }
}

extern "C" void kernel_launch(void* const* d_in, const int* in_sizes, int n_in,
                              void* d_out, int out_size, void* d_ws, size_t ws_size,
                              hipStream_t stream)
{
    const float* t     = (const float*)d_in[0];
    const float* W1    = (const float*)d_in[1];
    const float* b1    = (const float*)d_in[2];
    const float* g1    = (const float*)d_in[3];
    const float* beta1 = (const float*)d_in[4];
    const float* m1    = (const float*)d_in[5];
    const float* v1    = (const float*)d_in[6];
    const float* W2    = (const float*)d_in[7];
    const float* b2    = (const float*)d_in[8];
    const float* g2    = (const float*)d_in[9];
    const float* beta2 = (const float*)d_in[10];
    const float* m2    = (const float*)d_in[11];
    const float* v2    = (const float*)d_in[12];

    char* ws = (char*)d_ws;
    unsigned short* w1bf = (unsigned short*)(ws);                 //  8,388,608 B
    unsigned short* w2bf = (unsigned short*)(ws + 8388608);       //  8,388,608 B
    unsigned short* sbf  = (unsigned short*)(ws + 16777216);      //  4,194,304 B
    float* sc1 = (float*)(ws + 20971520);                         //     32,768 B
    float* bi1 = (float*)(ws + 21004288);                         //     32,768 B
    float* sc2 = (float*)(ws + 21037056);                         //    131,072 B
    float* bi2 = (float*)(ws + 21168128);                         //    131,072 B
    unsigned short* hbuf = (unsigned short*)(ws + 21299200);      // 67,108,864 B

    prep_kernel<<<4096, 256, 0, stream>>>(
        (const float4*)W1, (const float4*)W2,
        b1, g1, beta1, m1, v1, b2, g2, beta2, m2, v2,
        (ushort4*)w1bf, (ushort4*)w2bf, sc1, bi1, sc2, bi2);

    sum_kernel<<<2048, 256, 0, stream>>>(t, sbf);

    zero_kernel<<<2048, 256, 0, stream>>>((float4*)d_out);

    gemm1_kernel<<<dim3(32, 64), 256, 0, stream>>>(sbf, w1bf, sc1, bi1, hbuf);

    gemm2_kernel<<<dim3(64, 8, 4), 256, 0, stream>>>(t, hbuf, w2bf, sc2, bi2, (float*)d_out);
}